// Round 2
// baseline (2506.886 us; speedup 1.0000x reference)
//
#include <hip/hip_runtime.h>
#include <hip/hip_bf16.h>

#define H_DIM 4096
#define M_TOK 4096
#define V_DIM 32000

typedef unsigned short ushort_t;
typedef __attribute__((ext_vector_type(8))) short short8;
typedef __attribute__((ext_vector_type(4))) float f32x4;

__device__ __forceinline__ unsigned short f2bf(float f) {
    unsigned int u = __float_as_uint(f);
    u += 0x7FFFu + ((u >> 16) & 1u);   // round-to-nearest-even
    return (unsigned short)(u >> 16);
}

// async global -> LDS, 16B per lane (wave-uniform base + lane*16 layout)
__device__ __forceinline__ void gl2lds16(const void* g, void* l) {
    __builtin_amdgcn_global_load_lds(
        (const __attribute__((address_space(1))) unsigned int*)g,
        (__attribute__((address_space(3))) unsigned int*)l, 16, 0, 0);
}

// ---------------- fp32 -> bf16 cast ----------------
__global__ void cast_f32_bf16(const float* __restrict__ src,
                              ushort_t* __restrict__ dst, size_t n) {
    size_t i = ((size_t)blockIdx.x * 256 + threadIdx.x) * 8;
    if (i >= n) return;
    float4 a = *(const float4*)(src + i);
    float4 b = *(const float4*)(src + i + 4);
    short8 p = { (short)f2bf(a.x), (short)f2bf(a.y), (short)f2bf(a.z), (short)f2bf(a.w),
                 (short)f2bf(b.x), (short)f2bf(b.y), (short)f2bf(b.z), (short)f2bf(b.w) };
    *(short8*)(dst + i) = p;
}

// ============================================================================
// 256x256-tile, 512-thread, 8-wave, double-buffered 4-phase pipelined GEMM
// (T1 xcd-swizzle + T2 lds-xor-swizzle + T3/T4 counted-vmcnt phases + T5
//  setprio).  K-tile BK=64, NT=64 tiles.  LDS = 2 x (32KB A + 32KB B) = 128KB.
//
// Staging schedule: tile t+1's 8 rounds (1 round = 512thr x 16B = 64 rows)
// are issued 2/phase over [t-1.ph2, t-1.ph3, t.ph0, t.ph1].  Every phase:
// issue 2 loads -> s_waitcnt vmcnt(4) (retires loads issued 2 phases ago,
// never drains to 0) -> s_barrier -> ds_read -> setprio(1) 16 MFMA setprio(0)
// -> s_barrier.  Quadrant snake (qm0,qn0)(qm0,qn1)(qm1,qn1)(qm1,qn0) makes
// every overwrite target provably dead:
//   ph2 overwrites buf[c] A-qm0 rows (last read ph1); ph3 overwrites buf[c]
//   B-qn1 stripes (last read ph1).
// vmcnt ledger (steady, per thread): before phase issue = 4 outstanding,
// +2 issued, vmcnt(4) retires the 2 oldest. Chunk staged at phase P is
// retired by P+2's vmcnt + barrier, first ds_read at >= P+3.  Binding case:
// B-qn0 staged t.ph1 -> retired t.ph3 -> read t+1.ph0.  OK.
// ============================================================================
__global__ __launch_bounds__(512, 2) void gemm_fused8(
    const ushort_t* __restrict__ xb,   // bf16 x  [4096 x 4096]
    const ushort_t* __restrict__ wb,   // bf16 W  [32000 x 4096]
    const int*      __restrict__ y,    // [4096]
    float* __restrict__ sums,          // [4096] sum of exp(logit)
    float* __restrict__ label)         // [4096] label logit
{
    int i = blockIdx.x;
    // xcd-aware swizzle: 2000 blocks, blockIdx%8 = XCD; each XCD gets a
    // contiguous run of (ntile, mtile) pairs with mtile sweeping fastest.
    int g = (i & 7) * 250 + (i >> 3);
    int mtile = g & 15;
    int ntile = g >> 4;                // 0..124
    int m0 = mtile * 256;
    int n0 = ntile * 256;

    __shared__ ushort_t lA[2][256 * 64];   // 2 x 32 KB
    __shared__ ushort_t lB[2][256 * 64];   // 2 x 32 KB

    int t = threadIdx.x;
    int lane = t & 63;
    int wid = t >> 6;                  // 0..7
    int wm = (wid >> 2) * 128;         // wave row base (wr*128)
    int wn = (wid & 3) * 64;           // wave col base (wc*64)
    int lrow = lane & 15;
    int lko = (lane >> 4) * 8;
    int sw = (lane & 7) * 8;           // read-side xor swizzle

    // staging thread geometry
    int sr = t >> 3;                            // 0..63 (row within round)
    int strow = (sr & 31) + (sr >> 5) * 64;     // striped row (for B qn rounds)
    int cswel = ((t & 7) ^ (sr & 7)) * 8;       // pre-swizzled global chunk
    int ch8 = (t & 7) * 8;                      // linear LDS chunk
    const ushort_t* agb = xb + (size_t)m0 * H_DIM + cswel;
    const ushort_t* bgb = wb + (size_t)n0 * H_DIM + cswel;

#define ST_A(BUF, RB, KT) gl2lds16(agb + (size_t)((RB) + sr) * H_DIM + (KT), \
                                   &lA[BUF][((RB) + sr) * 64 + ch8])
#define ST_B(BUF, SB, KT) gl2lds16(bgb + (size_t)((SB) + strow) * H_DIM + (KT), \
                                   &lB[BUF][((SB) + strow) * 64 + ch8])

#define RD_A(C, QM) \
    _Pragma("unroll") for (int mi2 = 0; mi2 < 4; mi2++) { \
        af[mi2][0] = *(const short8*)&lA[C][(wm + (QM) * 64 + mi2 * 16 + lrow) * 64 + (lko ^ sw)]; \
        af[mi2][1] = *(const short8*)&lA[C][(wm + (QM) * 64 + mi2 * 16 + lrow) * 64 + ((32 + lko) ^ sw)]; \
    }
#define RD_B(C, QN) do { \
        bf[0][0] = *(const short8*)&lB[C][(wn + (QN) * 32 + lrow) * 64 + (lko ^ sw)]; \
        bf[0][1] = *(const short8*)&lB[C][(wn + (QN) * 32 + lrow) * 64 + ((32 + lko) ^ sw)]; \
        bf[1][0] = *(const short8*)&lB[C][(wn + (QN) * 32 + 16 + lrow) * 64 + (lko ^ sw)]; \
        bf[1][1] = *(const short8*)&lB[C][(wn + (QN) * 32 + 16 + lrow) * 64 + ((32 + lko) ^ sw)]; \
    } while (0)

#define MFMA16(QM, N0) \
    __builtin_amdgcn_s_setprio(1); \
    _Pragma("unroll") for (int mi2 = 0; mi2 < 4; mi2++) { \
        acc[(QM)*4+mi2][(N0)]   = __builtin_amdgcn_mfma_f32_16x16x32_bf16(af[mi2][0], bf[0][0], acc[(QM)*4+mi2][(N0)],   0, 0, 0); \
        acc[(QM)*4+mi2][(N0)]   = __builtin_amdgcn_mfma_f32_16x16x32_bf16(af[mi2][1], bf[0][1], acc[(QM)*4+mi2][(N0)],   0, 0, 0); \
        acc[(QM)*4+mi2][(N0)+1] = __builtin_amdgcn_mfma_f32_16x16x32_bf16(af[mi2][0], bf[1][0], acc[(QM)*4+mi2][(N0)+1], 0, 0, 0); \
        acc[(QM)*4+mi2][(N0)+1] = __builtin_amdgcn_mfma_f32_16x16x32_bf16(af[mi2][1], bf[1][1], acc[(QM)*4+mi2][(N0)+1], 0, 0, 0); \
    } \
    __builtin_amdgcn_s_setprio(0);

#define VM4 asm volatile("s_waitcnt vmcnt(4)" ::: "memory")
#define VM2 asm volatile("s_waitcnt vmcnt(2)" ::: "memory")
#define VM0 asm volatile("s_waitcnt vmcnt(0)" ::: "memory")
#define BAR __builtin_amdgcn_s_barrier()

// One K-tile: 4 phases.  C = compute buffer, NC = other buffer.
// DO01: stage tile t+1 rounds R4..R7 (ph0,ph1).  DO23: stage tile t+2
// rounds R0..R3 (ph2,ph3).  W0..W3: waitcnt statements.
#define TILE_BODY(C, NC, KT1, KT2, DO01, DO23, W0, W1, W2, W3) do { \
    /* ---- ph0: quad (qm0, qn0) ---- */ \
    if (DO01) { ST_A(NC, 64, KT1); ST_A(NC, 192, KT1); } \
    W0; BAR; \
    RD_A(C, 0); RD_B(C, 0); \
    MFMA16(0, 0); \
    BAR; \
    /* ---- ph1: quad (qm0, qn1) ---- */ \
    if (DO01) { ST_B(NC, 0, KT1); ST_B(NC, 128, KT1); } \
    W1; BAR; \
    RD_B(C, 1); \
    MFMA16(0, 2); \
    BAR; \
    /* ---- ph2: quad (qm1, qn1) ---- */ \
    if (DO23) { ST_A(C, 0, KT2); ST_A(C, 128, KT2); } \
    W2; BAR; \
    RD_A(C, 1); \
    MFMA16(1, 2); \
    BAR; \
    /* ---- ph3: quad (qm1, qn0) ---- */ \
    if (DO23) { ST_B(C, 32, KT2); ST_B(C, 160, KT2); } \
    W3; BAR; \
    RD_B(C, 0); \
    MFMA16(1, 0); \
    BAR; \
} while (0)

    f32x4 acc[8][4] = {};
    short8 af[4][2], bf[2][2];

    // ---- prologue: tile0 (8 rounds) -> buf0; tile1 R0..R3 -> buf1 ----
    ST_A(0, 0, 0);   ST_A(0, 128, 0);   // R0 R1 (A qm0)
    ST_B(0, 32, 0);  ST_B(0, 160, 0);   // R2 R3 (B qn1 stripes)
    ST_A(0, 64, 0);  ST_A(0, 192, 0);   // R4 R5 (A qm1)
    ST_B(0, 0, 0);   ST_B(0, 128, 0);   // R6 R7 (B qn0 stripes)
    ST_A(1, 0, 64);  ST_A(1, 128, 64);  // tile1 R0 R1
    ST_B(1, 32, 64); ST_B(1, 160, 64);  // tile1 R2 R3
    VM4;                                 // retire tile0's 8 loads
    BAR;

    // ---- main loop: t = 0..61 steady state ----
    int c = 0;
    for (int tt = 0; tt < 62; tt++) {
        TILE_BODY(c, c ^ 1, (tt + 1) * 64, (tt + 2) * 64, 1, 1, VM4, VM4, VM4, VM4);
        c ^= 1;
    }
    // ---- t = 62: stage tile 63 R4..R7 only; drain ph2/ph3 ----
    TILE_BODY(c, c ^ 1, 63 * 64, 0, 1, 0, VM4, VM4, VM2, VM0);
    c ^= 1;
    // ---- t = 63: no staging, no waits ----
    TILE_BODY(c, c, 0, 0, 0, 0, (void)0, (void)0, (void)0, (void)0);

    // ---- epilogue: label gather + exp row-sum -> atomicAdd ----
    // All acc[] indices compile-time (dynamic index demotes acc to scratch).
    int quad = lane >> 4;
    #pragma unroll
    for (int ai = 0; ai < 8; ai++) {
        #pragma unroll
        for (int ii = 0; ii < 4; ii++) {
            int row = wm + (ai >> 2) * 64 + (ai & 3) * 16 + quad * 4 + ii;
            int gm = m0 + row;
            int yv = y[gm];
            int cc = yv - n0 - wn;                 // C/D: col = lane&15
            #pragma unroll
            for (int ni = 0; ni < 4; ni++) {
                if (cc == ni * 16 + lrow) label[gm] = acc[ai][ni][ii];
            }
            float s = __expf(acc[ai][0][ii]) + __expf(acc[ai][1][ii]) +
                      __expf(acc[ai][2][ii]) + __expf(acc[ai][3][ii]);
            s += __shfl_xor(s, 1);
            s += __shfl_xor(s, 2);
            s += __shfl_xor(s, 4);
            s += __shfl_xor(s, 8);
            if (lrow == 0) atomicAdd(&sums[gm], s);
        }
    }
}

// ============================================================================
// Fallback (workspace too small for bf16 W): old 128x128 single-buffer kernel
// reading fp32 W directly.  Unchanged from R1.
// ============================================================================
#define BM 128
#define BN 128
#define BK 64
__global__ __launch_bounds__(256) void gemm_fused_f32(
    const ushort_t* __restrict__ xb,
    const float*    __restrict__ wf,
    const int*      __restrict__ y,
    float* __restrict__ sums,
    float* __restrict__ label)
{
    int i = blockIdx.x;
    int xcd = i & 7;
    int j = i >> 3;
    int nouter = j >> 5;
    int mt = j & 31;
    int ntile = xcd + 8 * nouter;
    if (ntile >= 250) return;
    int m0 = mt * BM;
    int n0 = ntile * BN;

    __shared__ ushort_t lA[BM * BK];
    __shared__ ushort_t lB[BN * BK];

    int t = threadIdx.x;
    int lane = t & 63;
    int wid = t >> 6;
    int wm = (wid >> 1) * 64;
    int wn = (wid & 1) * 64;
    int lrow = lane & 15;
    int lko = (lane >> 4) * 8;
    int sw = (lane & 7) * 8;

    f32x4 acc[4][4] = {};

    int csw = ((t & 7) ^ ((t >> 3) & 7)) * 8;
    const ushort_t* ag = xb + (size_t)(m0 + (t >> 3)) * H_DIM + csw;
    ushort_t* al = &lA[t * 8];
    const float* wg = wf + (size_t)(n0 + (t >> 1)) * H_DIM + (t & 1) * 32;
    int wrow = t >> 1;

    for (int kt = 0; kt < H_DIM; kt += BK) {
        #pragma unroll
        for (int r = 0; r < 4; r++)
            gl2lds16(ag + kt + (size_t)r * 32 * H_DIM, al + r * 2048);
        #pragma unroll
        for (int q = 0; q < 4; q++) {
            float4 v0 = *(const float4*)(wg + kt + 8 * q);
            float4 v1 = *(const float4*)(wg + kt + 8 * q + 4);
            short8 p = { (short)f2bf(v0.x), (short)f2bf(v0.y), (short)f2bf(v0.z), (short)f2bf(v0.w),
                         (short)f2bf(v1.x), (short)f2bf(v1.y), (short)f2bf(v1.z), (short)f2bf(v1.w) };
            int e = (t & 1) * 32 + 8 * q;
            *(short8*)(&lB[wrow * BK + (e ^ ((wrow & 7) * 8))]) = p;
        }
        __syncthreads();
        #pragma unroll
        for (int kk = 0; kk < BK; kk += 32) {
            short8 af[4], bfr[4];
            #pragma unroll
            for (int mi = 0; mi < 4; mi++)
                af[mi] = *(const short8*)&lA[(wm + mi * 16 + lrow) * BK + ((kk + lko) ^ sw)];
            #pragma unroll
            for (int ni = 0; ni < 4; ni++)
                bfr[ni] = *(const short8*)&lB[(wn + ni * 16 + lrow) * BK + ((kk + lko) ^ sw)];
            #pragma unroll
            for (int mi = 0; mi < 4; mi++)
                #pragma unroll
                for (int ni = 0; ni < 4; ni++)
                    acc[mi][ni] = __builtin_amdgcn_mfma_f32_16x16x32_bf16(
                        af[mi], bfr[ni], acc[mi][ni], 0, 0, 0);
        }
        __syncthreads();
    }

    int quad = lane >> 4;
    #pragma unroll
    for (int mi = 0; mi < 4; mi++) {
        #pragma unroll
        for (int ii = 0; ii < 4; ii++) {
            int row = wm + mi * 16 + quad * 4 + ii;
            int gm = m0 + row;
            int yv = y[gm];
            int cc = yv - n0 - wn;
            #pragma unroll
            for (int ni = 0; ni < 4; ni++) {
                if (cc == ni * 16 + lrow) label[gm] = acc[mi][ni][ii];
            }
            float s = __expf(acc[mi][0][ii]) + __expf(acc[mi][1][ii]) +
                      __expf(acc[mi][2][ii]) + __expf(acc[mi][3][ii]);
            s += __shfl_xor(s, 1);
            s += __shfl_xor(s, 2);
            s += __shfl_xor(s, 4);
            s += __shfl_xor(s, 8);
            if (lrow == 0) atomicAdd(&sums[gm], s);
        }
    }
}

// ---------------- finalize: per-seq avg + CPO loss ----------------
__global__ void finalize_loss(const float* __restrict__ sums,
                              const float* __restrict__ label,
                              const int* __restrict__ y,
                              float* __restrict__ out) {
    __shared__ float red[512];
    __shared__ float redc[512];
    __shared__ float s_lp[8], s_cnt[8];
    int t = threadIdx.x;
    for (int s = 0; s < 8; s++) {
        int idx = s * 512 + t;
        int yv = y[idx];
        float maskf = (yv != -100) ? 1.0f : 0.0f;
        float lp = (label[idx] - logf(sums[idx])) * maskf;
        red[t] = lp;
        redc[t] = maskf;
        __syncthreads();
        for (int off = 256; off > 0; off >>= 1) {
            if (t < off) { red[t] += red[t + off]; redc[t] += redc[t + off]; }
            __syncthreads();
        }
        if (t == 0) { s_lp[s] = red[0]; s_cnt[s] = redc[0]; }
        __syncthreads();
    }
    if (t == 0) {
        float pref = 0.0f, nll_num = 0.0f, nll_den = 0.0f;
        for (int b = 0; b < 4; b++) {
            float avgc = s_lp[b] / s_cnt[b];
            float avgr = s_lp[b + 4] / s_cnt[b + 4];
            float d = 0.1f * (avgc - avgr);
            float ls = fminf(d, 0.0f) - log1pf(expf(-fabsf(d)));
            pref += -ls;                       // LABEL_SMOOTHING = 0
            nll_num += s_lp[b];
            nll_den += s_cnt[b];
        }
        pref *= 0.25f;                         // / B (=4)
        float nll = -nll_num / nll_den;
        out[0] = nll + pref;                   // ALPHA = 1
    }
}

extern "C" void kernel_launch(void* const* d_in, const int* in_sizes, int n_in,
                              void* d_out, int out_size, void* d_ws, size_t ws_size,
                              hipStream_t stream) {
    const float* x = (const float*)d_in[0];   // [8,512,4096] fp32
    const int*   y = (const int*)d_in[1];     // [8,512] int32
    const float* W = (const float*)d_in[2];   // [32000,4096] fp32
    float* out = (float*)d_out;

    char* ws = (char*)d_ws;
    ushort_t* xb   = (ushort_t*)ws;                         // 33,554,432 B
    float* sums    = (float*)(ws + 33554432);               // 16,384 B
    float* label   = (float*)(ws + 33554432 + 16384);       // 16,384 B
    ushort_t* Wb   = (ushort_t*)(ws + 33587200);            // 262,144,000 B
    bool wpre = ws_size >= 295731200ull;

    hipMemsetAsync(sums, 0, 32768, stream);  // zero sums + label

    cast_f32_bf16<<<8192, 256, 0, stream>>>(x, xb, (size_t)16777216);
    if (wpre) {
        cast_f32_bf16<<<64000, 256, 0, stream>>>(W, Wb, (size_t)131072000);
        gemm_fused8<<<2000, 512, 0, stream>>>(xb, Wb, y, sums, label);
    } else {
        gemm_fused_f32<<<8192, 256, 0, stream>>>(xb, W, y, sums, label);
    }
    finalize_loss<<<1, 512, 0, stream>>>(sums, label, y, out);
}